// Round 1
// baseline (1358.284 us; speedup 1.0000x reference)
//
#include <hip/hip_runtime.h>

// Problem constants
#define NN   102400      // nodes
#define NE   3276800     // edges
#define TT   64          // in channels
#define HH   32          // hidden
#define BSC  16          // conv3 out channels
#define NG   256         // graphs
#define NC   9           // classes
#define F1   256         // fc1 out
#define F2   128         // fc2 out
#define FIN  6400        // 400*16, fc1 in

// ---------------- graph preprocessing ----------------

__global__ __launch_bounds__(256) void k_deg(const int* __restrict__ src,
                                             const float* __restrict__ w,
                                             float* __restrict__ deg) {
    int e = blockIdx.x * 256 + threadIdx.x;
    atomicAdd(&deg[src[e]], w[e]);
}

__global__ __launch_bounds__(256) void k_dinv(float* d) {
    int i = blockIdx.x * 256 + threadIdx.x;
    float v = d[i];
    d[i] = v > 0.f ? rsqrtf(v) : 0.f;
}

__global__ __launch_bounds__(256) void k_lapw(const int* __restrict__ src,
                                              const int* __restrict__ dst,
                                              const float* __restrict__ w,
                                              const float* __restrict__ dinv,
                                              float* __restrict__ lapw) {
    int e = blockIdx.x * 256 + threadIdx.x;
    lapw[e] = -dinv[src[e]] * w[e] * dinv[dst[e]];
}

// ---------------- per-node dual GEMM (h@W0 and h@W1) ----------------
// One thread per node. W addresses are lane-uniform -> compiler emits s_loads;
// accumulators live in VGPRs (COUT<=32 -> 2*COUT accs).
template<int CIN, int COUT>
__global__ __launch_bounds__(256) void k_dual_gemm(const float* __restrict__ in,
                                                   const float* __restrict__ W0,
                                                   const float* __restrict__ W1,
                                                   float* __restrict__ o0,
                                                   float* __restrict__ o1) {
    int node = blockIdx.x * 256 + threadIdx.x;
    const float* row = in + (size_t)node * CIN;
    float a0[COUT], a1[COUT];
#pragma unroll
    for (int c = 0; c < COUT; ++c) { a0[c] = 0.f; a1[c] = 0.f; }
    for (int k = 0; k < CIN; ++k) {
        float xv = row[k];
#pragma unroll
        for (int c = 0; c < COUT; ++c) {
            a0[c] = fmaf(xv, W0[k * COUT + c], a0[c]);
            a1[c] = fmaf(xv, W1[k * COUT + c], a1[c]);
        }
    }
#pragma unroll
    for (int c = 0; c < COUT; ++c) {
        o0[(size_t)node * COUT + c] = a0[c];
        o1[(size_t)node * COUT + c] = a1[c];
    }
}

// ---------------- edge scatter: tx[dst] += lapw * xw[src] ----------------
// 32 (or 16) lanes per edge: gathers and atomics are contiguous per edge row.
template<int C>
__global__ __launch_bounds__(256) void k_scatter(const int* __restrict__ src,
                                                 const int* __restrict__ dst,
                                                 const float* __restrict__ lapw,
                                                 const float* __restrict__ xw,
                                                 float* __restrict__ tx) {
    unsigned gid = blockIdx.x * 256u + threadIdx.x;
    unsigned e = gid / C;
    unsigned c = gid % C;
    float v = lapw[e];
    atomicAdd(&tx[(size_t)dst[e] * C + c], v * xw[(size_t)src[e] * C + c]);
}

// ---------------- h = relu(a + t + bias) ----------------
template<int C>
__global__ __launch_bounds__(256) void k_bias_relu(const float* __restrict__ a,
                                                   const float* __restrict__ t,
                                                   const float* __restrict__ b,
                                                   float* __restrict__ o) {
    int i = blockIdx.x * 256 + threadIdx.x;
    float v = a[i] + t[i] + b[i & (C - 1)];
    o[i] = v > 0.f ? v : 0.f;
}

// ---------------- collapsed FC head ----------------
// W23 = fc2_w @ fc3_w  [256,9]
__global__ __launch_bounds__(256) void k_w23(const float* __restrict__ fc2w,
                                             const float* __restrict__ fc3w,
                                             float* __restrict__ w23) {
    int gid = blockIdx.x * 256 + threadIdx.x;
    if (gid >= F1 * NC) return;
    int r = gid / NC, c = gid % NC;
    float acc = 0.f;
    for (int j = 0; j < F2; ++j) acc = fmaf(fc2w[r * F2 + j], fc3w[j * NC + c], acc);
    w23[gid] = acc;
}

// bc = fc1_b@W23 + fc2_b@fc3_w + fc3_b  [9]
__global__ __launch_bounds__(64) void k_bc(const float* __restrict__ fc1b,
                                           const float* __restrict__ fc2b,
                                           const float* __restrict__ fc3b,
                                           const float* __restrict__ fc3w,
                                           const float* __restrict__ w23,
                                           float* __restrict__ bc) {
    int c = threadIdx.x;
    if (c >= NC) return;
    float acc = fc3b[c];
    for (int k = 0; k < F1; ++k) acc = fmaf(fc1b[k], w23[k * NC + c], acc);
    for (int j = 0; j < F2; ++j) acc = fmaf(fc2b[j], fc3w[j * NC + c], acc);
    bc[c] = acc;
}

// T1 = fc1_w @ fc2_w  [6400,128]; block = 16 rows x 128 cols, 8 rows/thread
__global__ __launch_bounds__(256) void k_t1(const float* __restrict__ fc1w,
                                            const float* __restrict__ fc2w,
                                            float* __restrict__ t1) {
    int c = threadIdx.x & 127;
    int rh = threadIdx.x >> 7;            // 0..1
    int r0 = blockIdx.x * 16 + rh;        // rows r0 + 2*rr
    float acc[8];
#pragma unroll
    for (int rr = 0; rr < 8; ++rr) acc[rr] = 0.f;
    for (int k = 0; k < F1; ++k) {
        float wv = fc2w[k * F2 + c];
#pragma unroll
        for (int rr = 0; rr < 8; ++rr)
            acc[rr] = fmaf(fc1w[(r0 + rr * 2) * F1 + k], wv, acc[rr]);
    }
#pragma unroll
    for (int rr = 0; rr < 8; ++rr) t1[(r0 + rr * 2) * F2 + c] = acc[rr];
}

// Wc = T1 @ fc3_w  [6400,9] (col index padded to 16 lanes)
__global__ __launch_bounds__(256) void k_wc(const float* __restrict__ t1,
                                            const float* __restrict__ fc3w,
                                            float* __restrict__ wc) {
    int gid = blockIdx.x * 256 + threadIdx.x;
    int r = gid >> 4, c = gid & 15;
    if (c >= NC) return;
    float acc = 0.f;
    for (int j = 0; j < F2; ++j) acc = fmaf(t1[r * F2 + j], fc3w[j * NC + c], acc);
    wc[r * NC + c] = acc;
}

// out = h3.reshape(256,6400) @ Wc + bc   [256,9]; one block per graph
__global__ __launch_bounds__(256) void k_out(const float* __restrict__ h3,
                                             const float* __restrict__ wc,
                                             const float* __restrict__ bc,
                                             float* __restrict__ out) {
    __shared__ float red[256 * 10];
    int g = blockIdx.x, tid = threadIdx.x;
    float acc[NC];
#pragma unroll
    for (int c = 0; c < NC; ++c) acc[c] = 0.f;
    for (int k = tid; k < FIN; k += 256) {
        float hv = h3[(size_t)g * FIN + k];
#pragma unroll
        for (int c = 0; c < NC; ++c) acc[c] = fmaf(hv, wc[k * NC + c], acc[c]);
    }
#pragma unroll
    for (int c = 0; c < NC; ++c) red[tid * 10 + c] = acc[c];
    __syncthreads();
    for (int s = 128; s > 0; s >>= 1) {
        if (tid < s) {
#pragma unroll
            for (int c = 0; c < NC; ++c) red[tid * 10 + c] += red[(tid + s) * 10 + c];
        }
        __syncthreads();
    }
    if (tid < NC) out[g * NC + tid] = red[tid] + bc[tid];
}

// ---------------- launch ----------------

extern "C" void kernel_launch(void* const* d_in, const int* in_sizes, int n_in,
                              void* d_out, int out_size, void* d_ws, size_t ws_size,
                              hipStream_t stream) {
    const float* x    = (const float*)d_in[0];
    const int*   ei   = (const int*)d_in[1];
    const float* ew   = (const float*)d_in[2];
    const float* W1_0 = (const float*)d_in[3];
    const float* W1_1 = (const float*)d_in[4];
    const float* b1   = (const float*)d_in[5];
    const float* W2_0 = (const float*)d_in[6];
    const float* W2_1 = (const float*)d_in[7];
    const float* b2   = (const float*)d_in[8];
    const float* W3_0 = (const float*)d_in[9];
    const float* W3_1 = (const float*)d_in[10];
    const float* b3   = (const float*)d_in[11];
    const float* fc1w = (const float*)d_in[12];
    const float* fc1b = (const float*)d_in[13];
    const float* fc2w = (const float*)d_in[14];
    const float* fc2b = (const float*)d_in[15];
    const float* fc3w = (const float*)d_in[16];
    const float* fc3b = (const float*)d_in[17];
    float* out = (float*)d_out;
    float* ws  = (float*)d_ws;

    const int* src = ei;        // edge_index[0]
    const int* dst = ei + NE;   // edge_index[1]

    float* dinv = ws;                        // [NN]
    float* lapw = dinv + NN;                 // [NE]
    float* A    = lapw + NE;                 // [NN*32]
    float* B    = A + (size_t)NN * HH;       // [NN*32]
    float* C    = B + (size_t)NN * HH;       // [NN*32]
    float* D    = C + (size_t)NN * HH;       // [NN*32]
    float* w23  = D + (size_t)NN * HH;       // [256*9]
    float* bc   = w23 + F1 * NC;             // [9]

    // normalization
    hipMemsetAsync(dinv, 0, NN * sizeof(float), stream);
    k_deg<<<NE / 256, 256, 0, stream>>>(src, ew, dinv);
    k_dinv<<<NN / 256, 256, 0, stream>>>(dinv);
    k_lapw<<<NE / 256, 256, 0, stream>>>(src, dst, ew, dinv, lapw);

    // layer 1: 64 -> 32
    k_dual_gemm<TT, HH><<<NN / 256, 256, 0, stream>>>(x, W1_0, W1_1, A, B);
    hipMemsetAsync(C, 0, (size_t)NN * HH * sizeof(float), stream);
    k_scatter<HH><<<(unsigned)((size_t)NE * HH / 256), 256, 0, stream>>>(src, dst, lapw, B, C);
    k_bias_relu<HH><<<NN * HH / 256, 256, 0, stream>>>(A, C, b1, D);

    // layer 2: 32 -> 32
    k_dual_gemm<HH, HH><<<NN / 256, 256, 0, stream>>>(D, W2_0, W2_1, A, B);
    hipMemsetAsync(C, 0, (size_t)NN * HH * sizeof(float), stream);
    k_scatter<HH><<<(unsigned)((size_t)NE * HH / 256), 256, 0, stream>>>(src, dst, lapw, B, C);
    k_bias_relu<HH><<<NN * HH / 256, 256, 0, stream>>>(A, C, b2, D);

    // layer 3: 32 -> 16
    k_dual_gemm<HH, BSC><<<NN / 256, 256, 0, stream>>>(D, W3_0, W3_1, A, B);
    hipMemsetAsync(C, 0, (size_t)NN * BSC * sizeof(float), stream);
    k_scatter<BSC><<<(unsigned)((size_t)NE * BSC / 256), 256, 0, stream>>>(src, dst, lapw, B, C);
    k_bias_relu<BSC><<<NN * BSC / 256, 256, 0, stream>>>(A, C, b3, D);   // h3 in D [NN,16]

    // collapsed FC head
    k_w23<<<(F1 * NC + 255) / 256, 256, 0, stream>>>(fc2w, fc3w, w23);
    k_bc<<<1, 64, 0, stream>>>(fc1b, fc2b, fc3b, fc3w, w23, bc);
    float* T1 = A;   // [6400,128]
    k_t1<<<FIN / 16, 256, 0, stream>>>(fc1w, fc2w, T1);
    float* Wc = B;   // [6400,9]
    k_wc<<<FIN * 16 / 256, 256, 0, stream>>>(T1, fc3w, Wc);
    k_out<<<NG, 256, 0, stream>>>(D, Wc, bc, out);
}

// Round 2
// 1154.464 us; speedup vs baseline: 1.1765x; 1.1765x over previous
//
#include <hip/hip_runtime.h>

// Problem constants
#define NN   102400      // nodes
#define NE   3276800     // edges
#define TT   64          // in channels
#define HH   32          // hidden
#define BSC  16          // conv3 out channels
#define NG   256         // graphs
#define NC   9           // classes
#define F1   256         // fc1 out
#define F2   128         // fc2 out
#define FIN  6400        // 400*16, fc1 in

// ---------------- graph preprocessing ----------------

__global__ __launch_bounds__(256) void k_deg(const int* __restrict__ src,
                                             const float* __restrict__ w,
                                             float* __restrict__ deg) {
    int e = blockIdx.x * 256 + threadIdx.x;
    atomicAdd(&deg[src[e]], w[e]);
}

__global__ __launch_bounds__(256) void k_dinv(float* d) {
    int i = blockIdx.x * 256 + threadIdx.x;
    float v = d[i];
    d[i] = v > 0.f ? rsqrtf(v) : 0.f;
}

__global__ __launch_bounds__(256) void k_lapw(const int* __restrict__ src,
                                              const int* __restrict__ dst,
                                              const float* __restrict__ w,
                                              const float* __restrict__ dinv,
                                              float* __restrict__ lapw) {
    int e = blockIdx.x * 256 + threadIdx.x;
    lapw[e] = -dinv[src[e]] * w[e] * dinv[dst[e]];
}

// ---------------- counting sort by dst ----------------

__global__ __launch_bounds__(256) void k_hist(const int* __restrict__ dst,
                                              int* __restrict__ cnt) {
    int e = blockIdx.x * 256 + threadIdx.x;
    atomicAdd(&cnt[dst[e]], 1);
}

// per-block inclusive scan of cnt -> incl, block totals -> bsum
__global__ __launch_bounds__(256) void k_scan1(const int* __restrict__ cnt,
                                               int* __restrict__ incl,
                                               int* __restrict__ bsum) {
    __shared__ int s[256];
    int gid = blockIdx.x * 256 + threadIdx.x;
    int t = threadIdx.x;
    s[t] = cnt[gid];
    __syncthreads();
    for (int off = 1; off < 256; off <<= 1) {
        int add = (t >= off) ? s[t - off] : 0;
        __syncthreads();
        s[t] += add;
        __syncthreads();
    }
    incl[gid] = s[t];
    if (t == 255) bsum[blockIdx.x] = s[255];
}

// exclusive scan of the 400 block totals (single block of 512)
__global__ __launch_bounds__(512) void k_scan2(int* bsum) {
    __shared__ int s[512];
    int t = threadIdx.x;
    int v = (t < 400) ? bsum[t] : 0;
    s[t] = v;
    __syncthreads();
    for (int off = 1; off < 512; off <<= 1) {
        int add = (t >= off) ? s[t - off] : 0;
        __syncthreads();
        s[t] += add;
        __syncthreads();
    }
    if (t < 400) bsum[t] = s[t] - v;   // exclusive
}

// exclusive row starts -> rowptr and cursor; rowptr[NN] = NE
__global__ __launch_bounds__(256) void k_scan3(const int* __restrict__ incl,
                                               const int* __restrict__ cnt,
                                               const int* __restrict__ bsum,
                                               int* __restrict__ rowptr,
                                               int* __restrict__ cursor) {
    int gid = blockIdx.x * 256 + threadIdx.x;
    int excl = incl[gid] - cnt[gid] + bsum[blockIdx.x];
    rowptr[gid] = excl;
    cursor[gid] = excl;
    if (gid == 0) rowptr[NN] = NE;
}

// place packed payload {src, lapw} into dst-sorted order
__global__ __launch_bounds__(256) void k_place(const int* __restrict__ src,
                                               const int* __restrict__ dst,
                                               const float* __restrict__ lapw,
                                               int* __restrict__ cursor,
                                               int2* __restrict__ edata) {
    int e = blockIdx.x * 256 + threadIdx.x;
    int d = dst[e];
    int pos = atomicAdd(&cursor[d], 1);
    edata[pos] = make_int2(src[e], __float_as_int(lapw[e]));
}

// ---------------- per-node dual GEMM (h@W0 and h@W1) ----------------
template<int CIN, int COUT>
__global__ __launch_bounds__(256) void k_dual_gemm(const float* __restrict__ in,
                                                   const float* __restrict__ W0,
                                                   const float* __restrict__ W1,
                                                   float* __restrict__ o0,
                                                   float* __restrict__ o1) {
    int node = blockIdx.x * 256 + threadIdx.x;
    const float* row = in + (size_t)node * CIN;
    float a0[COUT], a1[COUT];
#pragma unroll
    for (int c = 0; c < COUT; ++c) { a0[c] = 0.f; a1[c] = 0.f; }
    for (int k = 0; k < CIN; ++k) {
        float xv = row[k];
#pragma unroll
        for (int c = 0; c < COUT; ++c) {
            a0[c] = fmaf(xv, W0[k * COUT + c], a0[c]);
            a1[c] = fmaf(xv, W1[k * COUT + c], a1[c]);
        }
    }
#pragma unroll
    for (int c = 0; c < COUT; ++c) {
        o0[(size_t)node * COUT + c] = a0[c];
        o1[(size_t)node * COUT + c] = a1[c];
    }
}

// ---------------- CSR gather: tx[n] = sum_{e in rows(n)} w_e * xw[src_e] ----
// C lanes per node; edata reads broadcast across the C-lane group; xw row
// reads are contiguous 4*C bytes. No atomics, each output written once.
template<int C>
__global__ __launch_bounds__(256) void k_gather(const int* __restrict__ rowptr,
                                                const int2* __restrict__ edata,
                                                const float* __restrict__ xw,
                                                float* __restrict__ out) {
    constexpr int NPB = 256 / C;
    int tid = threadIdx.x;
    int g = tid / C;
    int lane = tid % C;
    int node = blockIdx.x * NPB + g;
    int start = rowptr[node], end = rowptr[node + 1];
    float acc = 0.f;
    int j = start;
    for (; j + 1 < end; j += 2) {
        int2 e0 = edata[j];
        int2 e1 = edata[j + 1];
        float v0 = xw[(size_t)e0.x * C + lane];
        float v1 = xw[(size_t)e1.x * C + lane];
        acc = fmaf(__int_as_float(e0.y), v0, acc);
        acc = fmaf(__int_as_float(e1.y), v1, acc);
    }
    if (j < end) {
        int2 e0 = edata[j];
        acc = fmaf(__int_as_float(e0.y), xw[(size_t)e0.x * C + lane], acc);
    }
    out[(size_t)node * C + lane] = acc;
}

// ---------------- h = relu(a + t + bias) ----------------
template<int C>
__global__ __launch_bounds__(256) void k_bias_relu(const float* __restrict__ a,
                                                   const float* __restrict__ t,
                                                   const float* __restrict__ b,
                                                   float* __restrict__ o) {
    int i = blockIdx.x * 256 + threadIdx.x;
    float v = a[i] + t[i] + b[i & (C - 1)];
    o[i] = v > 0.f ? v : 0.f;
}

// ---------------- collapsed FC head ----------------
__global__ __launch_bounds__(256) void k_w23(const float* __restrict__ fc2w,
                                             const float* __restrict__ fc3w,
                                             float* __restrict__ w23) {
    int gid = blockIdx.x * 256 + threadIdx.x;
    if (gid >= F1 * NC) return;
    int r = gid / NC, c = gid % NC;
    float acc = 0.f;
    for (int j = 0; j < F2; ++j) acc = fmaf(fc2w[r * F2 + j], fc3w[j * NC + c], acc);
    w23[gid] = acc;
}

__global__ __launch_bounds__(64) void k_bc(const float* __restrict__ fc1b,
                                           const float* __restrict__ fc2b,
                                           const float* __restrict__ fc3b,
                                           const float* __restrict__ fc3w,
                                           const float* __restrict__ w23,
                                           float* __restrict__ bc) {
    int c = threadIdx.x;
    if (c >= NC) return;
    float acc = fc3b[c];
    for (int k = 0; k < F1; ++k) acc = fmaf(fc1b[k], w23[k * NC + c], acc);
    for (int j = 0; j < F2; ++j) acc = fmaf(fc2b[j], fc3w[j * NC + c], acc);
    bc[c] = acc;
}

__global__ __launch_bounds__(256) void k_t1(const float* __restrict__ fc1w,
                                            const float* __restrict__ fc2w,
                                            float* __restrict__ t1) {
    int c = threadIdx.x & 127;
    int rh = threadIdx.x >> 7;
    int r0 = blockIdx.x * 16 + rh;
    float acc[8];
#pragma unroll
    for (int rr = 0; rr < 8; ++rr) acc[rr] = 0.f;
    for (int k = 0; k < F1; ++k) {
        float wv = fc2w[k * F2 + c];
#pragma unroll
        for (int rr = 0; rr < 8; ++rr)
            acc[rr] = fmaf(fc1w[(r0 + rr * 2) * F1 + k], wv, acc[rr]);
    }
#pragma unroll
    for (int rr = 0; rr < 8; ++rr) t1[(r0 + rr * 2) * F2 + c] = acc[rr];
}

__global__ __launch_bounds__(256) void k_wc(const float* __restrict__ t1,
                                            const float* __restrict__ fc3w,
                                            float* __restrict__ wc) {
    int gid = blockIdx.x * 256 + threadIdx.x;
    int r = gid >> 4, c = gid & 15;
    if (c >= NC) return;
    float acc = 0.f;
    for (int j = 0; j < F2; ++j) acc = fmaf(t1[r * F2 + j], fc3w[j * NC + c], acc);
    wc[r * NC + c] = acc;
}

__global__ __launch_bounds__(256) void k_out(const float* __restrict__ h3,
                                             const float* __restrict__ wc,
                                             const float* __restrict__ bc,
                                             float* __restrict__ out) {
    __shared__ float red[256 * 10];
    int g = blockIdx.x, tid = threadIdx.x;
    float acc[NC];
#pragma unroll
    for (int c = 0; c < NC; ++c) acc[c] = 0.f;
    for (int k = tid; k < FIN; k += 256) {
        float hv = h3[(size_t)g * FIN + k];
#pragma unroll
        for (int c = 0; c < NC; ++c) acc[c] = fmaf(hv, wc[k * NC + c], acc[c]);
    }
#pragma unroll
    for (int c = 0; c < NC; ++c) red[tid * 10 + c] = acc[c];
    __syncthreads();
    for (int s = 128; s > 0; s >>= 1) {
        if (tid < s) {
#pragma unroll
            for (int c = 0; c < NC; ++c) red[tid * 10 + c] += red[(tid + s) * 10 + c];
        }
        __syncthreads();
    }
    if (tid < NC) out[g * NC + tid] = red[tid] + bc[tid];
}

// ---------------- launch ----------------

extern "C" void kernel_launch(void* const* d_in, const int* in_sizes, int n_in,
                              void* d_out, int out_size, void* d_ws, size_t ws_size,
                              hipStream_t stream) {
    const float* x    = (const float*)d_in[0];
    const int*   ei   = (const int*)d_in[1];
    const float* ew   = (const float*)d_in[2];
    const float* W1_0 = (const float*)d_in[3];
    const float* W1_1 = (const float*)d_in[4];
    const float* b1   = (const float*)d_in[5];
    const float* W2_0 = (const float*)d_in[6];
    const float* W2_1 = (const float*)d_in[7];
    const float* b2   = (const float*)d_in[8];
    const float* W3_0 = (const float*)d_in[9];
    const float* W3_1 = (const float*)d_in[10];
    const float* b3   = (const float*)d_in[11];
    const float* fc1w = (const float*)d_in[12];
    const float* fc1b = (const float*)d_in[13];
    const float* fc2w = (const float*)d_in[14];
    const float* fc2b = (const float*)d_in[15];
    const float* fc3w = (const float*)d_in[16];
    const float* fc3b = (const float*)d_in[17];
    float* out = (float*)d_out;
    float* ws  = (float*)d_ws;

    const int* src = ei;        // edge_index[0]
    const int* dst = ei + NE;   // edge_index[1]

    // workspace layout (floats). Aliasing (safe via stream ordering):
    //   lapw lives in Cb  (Cb first overwritten by layer-1 gather, after k_place)
    //   sort temps cnt/incl/cursor live in A (A first overwritten by layer-1 dual_gemm)
    float* dinv = ws;                           // [NN]
    float* A    = dinv + NN;                    // [NN*32]
    float* B    = A + (size_t)NN * HH;          // [NN*32]
    float* Cb   = B + (size_t)NN * HH;          // [NN*32] ; lapw alias (NE == NN*32)
    float* D    = Cb + (size_t)NN * HH;         // [NN*32]
    int2*  edata  = (int2*)(D + (size_t)NN * HH);   // [NE] packed {src, lapw}
    int*   rowptr = (int*)(edata + NE);         // [NN+1]
    int*   bsum   = rowptr + NN + 2;            // [512]
    float* w23    = (float*)(bsum + 512);       // [256*9]
    float* bc     = w23 + F1 * NC;              // [9]

    float* lapw = Cb;
    int* cnt    = (int*)A;
    int* incl   = cnt + NN;
    int* cursor = incl + NN;

    // normalization
    hipMemsetAsync(dinv, 0, NN * sizeof(float), stream);
    hipMemsetAsync(cnt, 0, NN * sizeof(int), stream);
    k_deg<<<NE / 256, 256, 0, stream>>>(src, ew, dinv);
    k_dinv<<<NN / 256, 256, 0, stream>>>(dinv);
    k_lapw<<<NE / 256, 256, 0, stream>>>(src, dst, ew, dinv, lapw);

    // counting sort by dst -> CSR (rowptr, edata)
    k_hist<<<NE / 256, 256, 0, stream>>>(dst, cnt);
    k_scan1<<<NN / 256, 256, 0, stream>>>(cnt, incl, bsum);
    k_scan2<<<1, 512, 0, stream>>>(bsum);
    k_scan3<<<NN / 256, 256, 0, stream>>>(incl, cnt, bsum, rowptr, cursor);
    k_place<<<NE / 256, 256, 0, stream>>>(src, dst, lapw, cursor, edata);

    // layer 1: 64 -> 32
    k_dual_gemm<TT, HH><<<NN / 256, 256, 0, stream>>>(x, W1_0, W1_1, A, B);
    k_gather<HH><<<NN / 8, 256, 0, stream>>>(rowptr, edata, B, Cb);
    k_bias_relu<HH><<<NN * HH / 256, 256, 0, stream>>>(A, Cb, b1, D);

    // layer 2: 32 -> 32
    k_dual_gemm<HH, HH><<<NN / 256, 256, 0, stream>>>(D, W2_0, W2_1, A, B);
    k_gather<HH><<<NN / 8, 256, 0, stream>>>(rowptr, edata, B, Cb);
    k_bias_relu<HH><<<NN * HH / 256, 256, 0, stream>>>(A, Cb, b2, D);

    // layer 3: 32 -> 16
    k_dual_gemm<HH, BSC><<<NN / 256, 256, 0, stream>>>(D, W3_0, W3_1, A, B);
    k_gather<BSC><<<NN / 16, 256, 0, stream>>>(rowptr, edata, B, Cb);
    k_bias_relu<BSC><<<NN * BSC / 256, 256, 0, stream>>>(A, Cb, b3, D);  // h3 in D

    // collapsed FC head
    k_w23<<<(F1 * NC + 255) / 256, 256, 0, stream>>>(fc2w, fc3w, w23);
    k_bc<<<1, 64, 0, stream>>>(fc1b, fc2b, fc3b, fc3w, w23, bc);
    float* T1 = A;   // [6400,128]
    k_t1<<<FIN / 16, 256, 0, stream>>>(fc1w, fc2w, T1);
    float* Wc = B;   // [6400,9]
    k_wc<<<FIN * 16 / 256, 256, 0, stream>>>(T1, fc3w, Wc);
    k_out<<<NG, 256, 0, stream>>>(D, Wc, bc, out);
}

// Round 4
// 929.481 us; speedup vs baseline: 1.4613x; 1.2421x over previous
//
#include <hip/hip_runtime.h>

// Problem constants
#define NN   102400      // nodes
#define NE   3276800     // edges
#define TT   64          // in channels
#define HH   32          // hidden
#define BSC  16          // conv3 out channels
#define NG   256         // graphs
#define NC   9           // classes
#define F1   256         // fc1 out
#define F2   128         // fc2 out
#define FIN  6400        // 400*16, fc1 in

#define NBUCK 200        // NN / 512 dst buckets
#define TILE  8192       // edges per k_part1 workgroup (NE/TILE = 400 wgs)

// ---------------- fused preprocessing: deg (by src) + hist (by dst) --------

__global__ __launch_bounds__(256) void k_prep(const int* __restrict__ src,
                                              const int* __restrict__ dst,
                                              const float* __restrict__ w,
                                              float* __restrict__ deg,
                                              int* __restrict__ cnt) {
    int e = blockIdx.x * 256 + threadIdx.x;
    atomicAdd(&deg[src[e]], w[e]);
    atomicAdd(&cnt[dst[e]], 1);
}

__global__ __launch_bounds__(256) void k_dinv(float* d) {
    int i = blockIdx.x * 256 + threadIdx.x;
    float v = d[i];
    d[i] = v > 0.f ? rsqrtf(v) : 0.f;
}

// ---------------- scans: cnt -> rowptr (exclusive), gcur init --------------

__global__ __launch_bounds__(256) void k_scan1(const int* __restrict__ cnt,
                                               int* __restrict__ incl,
                                               int* __restrict__ bsum) {
    __shared__ int s[256];
    int gid = blockIdx.x * 256 + threadIdx.x;
    int t = threadIdx.x;
    s[t] = cnt[gid];
    __syncthreads();
    for (int off = 1; off < 256; off <<= 1) {
        int add = (t >= off) ? s[t - off] : 0;
        __syncthreads();
        s[t] += add;
        __syncthreads();
    }
    incl[gid] = s[t];
    if (t == 255) bsum[blockIdx.x] = s[255];
}

__global__ __launch_bounds__(512) void k_scan2(int* bsum) {
    __shared__ int s[512];
    int t = threadIdx.x;
    int v = (t < 400) ? bsum[t] : 0;
    s[t] = v;
    __syncthreads();
    for (int off = 1; off < 512; off <<= 1) {
        int add = (t >= off) ? s[t - off] : 0;
        __syncthreads();
        s[t] += add;
        __syncthreads();
    }
    if (t < 400) bsum[t] = s[t] - v;   // exclusive
}

__global__ __launch_bounds__(256) void k_scan3(const int* __restrict__ incl,
                                               const int* __restrict__ cnt,
                                               const int* __restrict__ bsum,
                                               int* __restrict__ rowptr,
                                               int* __restrict__ gcur) {
    int gid = blockIdx.x * 256 + threadIdx.x;
    int excl = incl[gid] - cnt[gid] + bsum[blockIdx.x];
    rowptr[gid] = excl;
    if ((gid & 511) == 0) gcur[gid >> 9] = excl;  // bucket write-claim cursors
    if (gid == 0) rowptr[NN] = NE;
}

// ---------------- pass 1: LDS-staged radix partition by dst>>9 -------------
// Payload: {src<<9 | (dst&511), lapw}. lapw computed inline (dinv L2-resident).
__global__ __launch_bounds__(256) void k_part1(const int* __restrict__ src,
                                               const int* __restrict__ dst,
                                               const float* __restrict__ ew,
                                               const float* __restrict__ dinv,
                                               int* __restrict__ gcur,
                                               int2* __restrict__ ebuck) {
    __shared__ int hist[256];
    __shared__ int base[256];
    __shared__ int cur[256];
    __shared__ int gpos[256];
    __shared__ int2 stage[TILE];
    __shared__ unsigned char bkt[TILE];

    int t = threadIdx.x;
    int e0 = blockIdx.x * TILE;

    hist[t] = 0;
    __syncthreads();
    // phase 1: tile histogram
#pragma unroll
    for (int i = 0; i < TILE / 256; ++i) {
        int d = dst[e0 + i * 256 + t];
        atomicAdd(&hist[d >> 9], 1);
    }
    __syncthreads();
    // phase 2: exclusive scan of hist -> base (256-wide LDS scan)
    int h = hist[t];
    base[t] = h;
    __syncthreads();
    for (int off = 1; off < 256; off <<= 1) {
        int add = (t >= off) ? base[t - off] : 0;
        __syncthreads();
        base[t] += add;
        __syncthreads();
    }
    int excl = base[t] - h;
    __syncthreads();
    base[t] = excl;
    cur[t] = excl;
    __syncthreads();
    // phase 3: place into LDS, compute lapw inline
#pragma unroll
    for (int i = 0; i < TILE / 256; ++i) {
        int e = e0 + i * 256 + t;
        int d = dst[e];
        int sr = src[e];
        float lw = -dinv[sr] * ew[e] * dinv[d];
        int b = d >> 9;
        int p = atomicAdd(&cur[b], 1);
        stage[p] = make_int2((sr << 9) | (d & 511), __float_as_int(lw));
        bkt[p] = (unsigned char)b;
    }
    __syncthreads();
    // phase 4: claim contiguous global ranges
    if (t < NBUCK && h > 0) gpos[t] = atomicAdd(&gcur[t], h);
    __syncthreads();
    // phase 5: coalesced flush
#pragma unroll
    for (int i = 0; i < TILE / 256; ++i) {
        int p = i * 256 + t;
        int b = bkt[p];
        ebuck[gpos[b] + (p - base[b])] = stage[p];
    }
}

// ---------------- pass 2: per-bucket CSR finalize (LDS cursors) ------------
__global__ __launch_bounds__(256) void k_part2(const int* __restrict__ rowptr,
                                               const int2* __restrict__ ebuck,
                                               int2* __restrict__ edata) {
    __shared__ int cur2[512];
    int b = blockIdx.x;
    int t = threadIdx.x;
    int lo = rowptr[b * 512];
    int hi = rowptr[(b + 1) * 512];
    cur2[t] = rowptr[b * 512 + t];
    cur2[t + 256] = rowptr[b * 512 + t + 256];
    __syncthreads();
    for (int j = lo + t; j < hi; j += 256) {
        int2 e = ebuck[j];
        int dlow = e.x & 511;
        int slot = atomicAdd(&cur2[dlow], 1);
        edata[slot] = make_int2(e.x >> 9, e.y);   // {src, lapw bits}
    }
}

// ---------------- per-node dual GEMM (h@W0 and h@W1) ----------------
template<int CIN, int COUT>
__global__ __launch_bounds__(256) void k_dual_gemm(const float* __restrict__ in,
                                                   const float* __restrict__ W0,
                                                   const float* __restrict__ W1,
                                                   float* __restrict__ o0,
                                                   float* __restrict__ o1) {
    int node = blockIdx.x * 256 + threadIdx.x;
    const float* row = in + (size_t)node * CIN;
    float a0[COUT], a1[COUT];
#pragma unroll
    for (int c = 0; c < COUT; ++c) { a0[c] = 0.f; a1[c] = 0.f; }
    for (int k = 0; k < CIN; ++k) {
        float xv = row[k];
#pragma unroll
        for (int c = 0; c < COUT; ++c) {
            a0[c] = fmaf(xv, W0[k * COUT + c], a0[c]);
            a1[c] = fmaf(xv, W1[k * COUT + c], a1[c]);
        }
    }
#pragma unroll
    for (int c = 0; c < COUT; ++c) {
        o0[(size_t)node * COUT + c] = a0[c];
        o1[(size_t)node * COUT + c] = a1[c];
    }
}

// ---------------- CSR gather fused with bias+relu --------------------------
// out[n,c] = relu(a[n,c] + sum_e lapw_e * xw[src_e, c] + bias[c])
template<int C>
__global__ __launch_bounds__(256) void k_gather(const int* __restrict__ rowptr,
                                                const int2* __restrict__ edata,
                                                const float* __restrict__ xw,
                                                const float* __restrict__ a,
                                                const float* __restrict__ bias,
                                                float* __restrict__ out) {
    constexpr int NPB = 256 / C;
    int tid = threadIdx.x;
    int g = tid / C;
    int lane = tid % C;
    int node = blockIdx.x * NPB + g;
    int start = rowptr[node], end = rowptr[node + 1];
    float acc = 0.f;
    int j = start;
    for (; j + 1 < end; j += 2) {
        int2 e0 = edata[j];
        int2 e1 = edata[j + 1];
        float v0 = xw[(size_t)e0.x * C + lane];
        float v1 = xw[(size_t)e1.x * C + lane];
        acc = fmaf(__int_as_float(e0.y), v0, acc);
        acc = fmaf(__int_as_float(e1.y), v1, acc);
    }
    if (j < end) {
        int2 e0 = edata[j];
        acc = fmaf(__int_as_float(e0.y), xw[(size_t)e0.x * C + lane], acc);
    }
    float v = a[(size_t)node * C + lane] + acc + bias[lane];
    out[(size_t)node * C + lane] = v > 0.f ? v : 0.f;
}

// ---------------- collapsed FC head ----------------
__global__ __launch_bounds__(256) void k_w23(const float* __restrict__ fc2w,
                                             const float* __restrict__ fc3w,
                                             float* __restrict__ w23) {
    int gid = blockIdx.x * 256 + threadIdx.x;
    if (gid >= F1 * NC) return;
    int r = gid / NC, c = gid % NC;
    float acc = 0.f;
    for (int j = 0; j < F2; ++j) acc = fmaf(fc2w[r * F2 + j], fc3w[j * NC + c], acc);
    w23[gid] = acc;
}

__global__ __launch_bounds__(64) void k_bc(const float* __restrict__ fc1b,
                                           const float* __restrict__ fc2b,
                                           const float* __restrict__ fc3b,
                                           const float* __restrict__ fc3w,
                                           const float* __restrict__ w23,
                                           float* __restrict__ bc) {
    int c = threadIdx.x;
    if (c >= NC) return;
    float acc = fc3b[c];
    for (int k = 0; k < F1; ++k) acc = fmaf(fc1b[k], w23[k * NC + c], acc);
    for (int j = 0; j < F2; ++j) acc = fmaf(fc2b[j], fc3w[j * NC + c], acc);
    bc[c] = acc;
}

__global__ __launch_bounds__(256) void k_t1(const float* __restrict__ fc1w,
                                            const float* __restrict__ fc2w,
                                            float* __restrict__ t1) {
    int c = threadIdx.x & 127;
    int rh = threadIdx.x >> 7;
    int r0 = blockIdx.x * 16 + rh;
    float acc[8];
#pragma unroll
    for (int rr = 0; rr < 8; ++rr) acc[rr] = 0.f;
    for (int k = 0; k < F1; ++k) {
        float wv = fc2w[k * F2 + c];
#pragma unroll
        for (int rr = 0; rr < 8; ++rr)
            acc[rr] = fmaf(fc1w[(r0 + rr * 2) * F1 + k], wv, acc[rr]);
    }
#pragma unroll
    for (int rr = 0; rr < 8; ++rr) t1[(r0 + rr * 2) * F2 + c] = acc[rr];
}

__global__ __launch_bounds__(256) void k_wc(const float* __restrict__ t1,
                                            const float* __restrict__ fc3w,
                                            float* __restrict__ wc) {
    int gid = blockIdx.x * 256 + threadIdx.x;
    int r = gid >> 4, c = gid & 15;
    if (c >= NC) return;
    float acc = 0.f;
    for (int j = 0; j < F2; ++j) acc = fmaf(t1[r * F2 + j], fc3w[j * NC + c], acc);
    wc[r * NC + c] = acc;
}

__global__ __launch_bounds__(256) void k_out(const float* __restrict__ h3,
                                             const float* __restrict__ wc,
                                             const float* __restrict__ bc,
                                             float* __restrict__ out) {
    __shared__ float red[256 * 10];
    int g = blockIdx.x, tid = threadIdx.x;
    float acc[NC];
#pragma unroll
    for (int c = 0; c < NC; ++c) acc[c] = 0.f;
    for (int k = tid; k < FIN; k += 256) {
        float hv = h3[(size_t)g * FIN + k];
#pragma unroll
        for (int c = 0; c < NC; ++c) acc[c] = fmaf(hv, wc[k * NC + c], acc[c]);
    }
#pragma unroll
    for (int c = 0; c < NC; ++c) red[tid * 10 + c] = acc[c];
    __syncthreads();
    for (int s = 128; s > 0; s >>= 1) {
        if (tid < s) {
#pragma unroll
            for (int c = 0; c < NC; ++c) red[tid * 10 + c] += red[(tid + s) * 10 + c];
        }
        __syncthreads();
    }
    if (tid < NC) out[g * NC + tid] = red[tid] + bc[tid];
}

// ---------------- launch ----------------

extern "C" void kernel_launch(void* const* d_in, const int* in_sizes, int n_in,
                              void* d_out, int out_size, void* d_ws, size_t ws_size,
                              hipStream_t stream) {
    const float* x    = (const float*)d_in[0];
    const int*   ei   = (const int*)d_in[1];
    const float* ew   = (const float*)d_in[2];
    const float* W1_0 = (const float*)d_in[3];
    const float* W1_1 = (const float*)d_in[4];
    const float* b1   = (const float*)d_in[5];
    const float* W2_0 = (const float*)d_in[6];
    const float* W2_1 = (const float*)d_in[7];
    const float* b2   = (const float*)d_in[8];
    const float* W3_0 = (const float*)d_in[9];
    const float* W3_1 = (const float*)d_in[10];
    const float* b3   = (const float*)d_in[11];
    const float* fc1w = (const float*)d_in[12];
    const float* fc1b = (const float*)d_in[13];
    const float* fc2w = (const float*)d_in[14];
    const float* fc2b = (const float*)d_in[15];
    const float* fc3w = (const float*)d_in[16];
    const float* fc3b = (const float*)d_in[17];
    float* out = (float*)d_out;
    float* ws  = (float*)d_ws;

    const int* src = ei;        // edge_index[0]
    const int* dst = ei + NE;   // edge_index[1]

    // workspace layout. ebuck aliases B+D exactly (NE*8 == 2*NN*HH*4);
    // ebuck is dead before the first dual_gemm writes A/B. cnt/incl alias A
    // (dead before dual_gemm layer 1).
    float* dinv = ws;                              // [NN]
    float* A    = dinv + NN;                       // [NN*32]
    float* B    = A + (size_t)NN * HH;             // [NN*32]
    float* D    = B + (size_t)NN * HH;             // [NN*32]
    int2*  edata  = (int2*)(D + (size_t)NN * HH);  // [NE] final CSR payload
    int*   rowptr = (int*)(edata + NE);            // [NN+1]
    int*   bsum   = rowptr + NN + 2;               // [512]
    int*   gcur   = bsum + 512;                    // [256]
    float* w23    = (float*)(gcur + 256);          // [256*9]
    float* bc     = w23 + F1 * NC;                 // [9]

    int2* ebuck = (int2*)B;                        // [NE] bucket-partitioned
    int*  cnt   = (int*)A;
    int*  incl  = cnt + NN;

    // preprocessing: degree + dst histogram + dinv
    hipMemsetAsync(dinv, 0, NN * sizeof(float), stream);
    hipMemsetAsync(cnt, 0, NN * sizeof(int), stream);
    k_prep<<<NE / 256, 256, 0, stream>>>(src, dst, ew, dinv, cnt);
    k_dinv<<<NN / 256, 256, 0, stream>>>(dinv);

    // rowptr (exclusive scan of cnt) + bucket claim cursors
    k_scan1<<<NN / 256, 256, 0, stream>>>(cnt, incl, bsum);
    k_scan2<<<1, 512, 0, stream>>>(bsum);
    k_scan3<<<NN / 256, 256, 0, stream>>>(incl, cnt, bsum, rowptr, gcur);

    // two-pass radix partition -> dst-sorted CSR payload (lapw fused in)
    k_part1<<<NE / TILE, 256, 0, stream>>>(src, dst, ew, dinv, gcur, ebuck);
    k_part2<<<NBUCK, 256, 0, stream>>>(rowptr, ebuck, edata);

    // layer 1: 64 -> 32
    k_dual_gemm<TT, HH><<<NN / 256, 256, 0, stream>>>(x, W1_0, W1_1, A, B);
    k_gather<HH><<<NN / 8, 256, 0, stream>>>(rowptr, edata, B, A, b1, D);

    // layer 2: 32 -> 32
    k_dual_gemm<HH, HH><<<NN / 256, 256, 0, stream>>>(D, W2_0, W2_1, A, B);
    k_gather<HH><<<NN / 8, 256, 0, stream>>>(rowptr, edata, B, A, b2, D);

    // layer 3: 32 -> 16
    k_dual_gemm<HH, BSC><<<NN / 256, 256, 0, stream>>>(D, W3_0, W3_1, A, B);
    k_gather<BSC><<<NN / 16, 256, 0, stream>>>(rowptr, edata, B, A, b3, D); // h3 in D

    // collapsed FC head
    k_w23<<<(F1 * NC + 255) / 256, 256, 0, stream>>>(fc2w, fc3w, w23);
    k_bc<<<1, 64, 0, stream>>>(fc1b, fc2b, fc3b, fc3w, w23, bc);
    float* T1 = A;   // [6400,128]
    k_t1<<<FIN / 16, 256, 0, stream>>>(fc1w, fc2w, T1);
    float* Wc = B;   // [6400,9]
    k_wc<<<FIN * 16 / 256, 256, 0, stream>>>(T1, fc3w, Wc);
    k_out<<<NG, 256, 0, stream>>>(D, Wc, bc, out);
}

// Round 6
// 701.631 us; speedup vs baseline: 1.9359x; 1.3247x over previous
//
#include <hip/hip_runtime.h>

// Problem constants
#define NN   102400      // nodes
#define NE   3276800     // edges
#define TT   64          // in channels
#define HH   32          // hidden
#define BSC  16          // conv3 out channels
#define NG   256         // graphs
#define NC   9           // classes
#define F1   256         // fc1 out
#define F2   128         // fc2 out
#define FIN  6400        // 400*16, fc1 in

#define NBUCK 200        // NN / 512 buckets (by node>>9)
#define CAP   18432      // slots per bucket region (mean 16384, +16 sigma)
#define TILE  8192       // edges per partition workgroup (NE/TILE = 400 wgs)

// ---------------- bucket cursor init ----------------

__global__ __launch_bounds__(256) void k_init(int* __restrict__ scur,
                                              int* __restrict__ dcur) {
    int t = threadIdx.x;
    if (t < NBUCK) { scur[t] = t * CAP; dcur[t] = t * CAP; }
}

// ---------------- LDS-staged partition by (src|dst)>>9 ----------------
// MODE 0: bucket by src, payload {src&511, ew}
// MODE 1: bucket by dst, payload {(src<<9)|(dst&511), ew}
template<int MODE>
__global__ __launch_bounds__(256) void k_part(const int* __restrict__ src,
                                              const int* __restrict__ dst,
                                              const float* __restrict__ ew,
                                              int* __restrict__ gcur,
                                              int2* __restrict__ outbuf) {
    __shared__ int hist[256];
    __shared__ int base[256];
    __shared__ int cur[256];
    __shared__ int gpos[256];
    __shared__ int2 stage[TILE];
    __shared__ unsigned char bkt[TILE];

    int t = threadIdx.x;
    int e0 = blockIdx.x * TILE;

    hist[t] = 0;
    __syncthreads();
    // phase 1: tile histogram
#pragma unroll
    for (int i = 0; i < TILE / 256; ++i) {
        int e = e0 + i * 256 + t;
        int key = MODE ? dst[e] : src[e];
        atomicAdd(&hist[key >> 9], 1);
    }
    __syncthreads();
    // phase 2: exclusive scan -> base
    int h = hist[t];
    base[t] = h;
    __syncthreads();
    for (int off = 1; off < 256; off <<= 1) {
        int add = (t >= off) ? base[t - off] : 0;
        __syncthreads();
        base[t] += add;
        __syncthreads();
    }
    int excl = base[t] - h;
    __syncthreads();
    base[t] = excl;
    cur[t] = excl;
    __syncthreads();
    // phase 3: place into LDS
#pragma unroll
    for (int i = 0; i < TILE / 256; ++i) {
        int e = e0 + i * 256 + t;
        int s = src[e];
        int w = __float_as_int(ew[e]);
        int key, pack;
        if (MODE) { int d = dst[e]; key = d; pack = (s << 9) | (d & 511); }
        else      { key = s; pack = s & 511; }
        int b = key >> 9;
        int p = atomicAdd(&cur[b], 1);
        stage[p] = make_int2(pack, w);
        bkt[p] = (unsigned char)b;
    }
    __syncthreads();
    // phase 4: claim contiguous global ranges in this bucket's region
    if (t < NBUCK && h > 0) gpos[t] = atomicAdd(&gcur[t], h);
    __syncthreads();
    // phase 5: coalesced flush
#pragma unroll
    for (int i = 0; i < TILE / 256; ++i) {
        int p = i * 256 + t;
        int b = bkt[p];
        outbuf[gpos[b] + (p - base[b])] = stage[p];
    }
}

// ---------------- per-src-bucket weighted degree -> dinv (LDS histogram) ---

__global__ __launch_bounds__(512) void k_deg2(const int* __restrict__ scur,
                                              const int2* __restrict__ sbuck,
                                              float* __restrict__ dinv) {
    __shared__ float acc[512];
    int b = blockIdx.x, t = threadIdx.x;
    acc[t] = 0.f;
    __syncthreads();
    int lo = b * CAP, hi = scur[b];
    for (int j = lo + t; j < hi; j += 512) {
        int2 e = sbuck[j];
        atomicAdd(&acc[e.x], __int_as_float(e.y));
    }
    __syncthreads();
    float v = acc[t];
    dinv[b * 512 + t] = v > 0.f ? rsqrtf(v) : 0.f;
}

// ---------------- per-dst-bucket CSR finalize (LDS hist+scan+cursors) ------
// edata[slot] = {src, lapw}; rowbeg/rowend delimit each node's edges.

__global__ __launch_bounds__(512) void k_fin(const int* __restrict__ dcur,
                                             const int2* __restrict__ dbuck,
                                             const float* __restrict__ dinv,
                                             int2* __restrict__ edata,
                                             int* __restrict__ rowbeg,
                                             int* __restrict__ rowend) {
    __shared__ float dl[512];
    __shared__ int cnt[512];
    __shared__ int base[512];
    __shared__ int cur[512];
    int b = blockIdx.x, t = threadIdx.x;
    dl[t] = dinv[b * 512 + t];
    cnt[t] = 0;
    __syncthreads();
    int lo = b * CAP, hi = dcur[b];
    for (int j = lo + t; j < hi; j += 512)
        atomicAdd(&cnt[dbuck[j].x & 511], 1);
    __syncthreads();
    int h = cnt[t];
    base[t] = h;
    __syncthreads();
    for (int off = 1; off < 512; off <<= 1) {
        int add = (t >= off) ? base[t - off] : 0;
        __syncthreads();
        base[t] += add;
        __syncthreads();
    }
    int beg = lo + base[t] - h;
    rowbeg[b * 512 + t] = beg;
    rowend[b * 512 + t] = beg + h;
    cur[t] = beg;
    __syncthreads();
    for (int j = lo + t; j < hi; j += 512) {
        int2 e = dbuck[j];
        int dlow = e.x & 511;
        int s = e.x >> 9;
        float lw = -dinv[s] * __int_as_float(e.y) * dl[dlow];
        int slot = atomicAdd(&cur[dlow], 1);
        edata[slot] = make_int2(s, __float_as_int(lw));
    }
}

// ---------------- per-node dual GEMM (h@W0 and h@W1) ----------------
template<int CIN, int COUT>
__global__ __launch_bounds__(256) void k_dual_gemm(const float* __restrict__ in,
                                                   const float* __restrict__ W0,
                                                   const float* __restrict__ W1,
                                                   float* __restrict__ o0,
                                                   float* __restrict__ o1) {
    int node = blockIdx.x * 256 + threadIdx.x;
    const float* row = in + (size_t)node * CIN;
    float a0[COUT], a1[COUT];
#pragma unroll
    for (int c = 0; c < COUT; ++c) { a0[c] = 0.f; a1[c] = 0.f; }
    for (int k = 0; k < CIN; ++k) {
        float xv = row[k];
#pragma unroll
        for (int c = 0; c < COUT; ++c) {
            a0[c] = fmaf(xv, W0[k * COUT + c], a0[c]);
            a1[c] = fmaf(xv, W1[k * COUT + c], a1[c]);
        }
    }
#pragma unroll
    for (int c = 0; c < COUT; ++c) {
        o0[(size_t)node * COUT + c] = a0[c];
        o1[(size_t)node * COUT + c] = a1[c];
    }
}

// ---------------- CSR gather fused with bias+relu --------------------------
// out[n,c] = relu(a[n,c] + sum_e lapw_e * xw[src_e, c] + bias[c])
template<int C>
__global__ __launch_bounds__(256) void k_gather(const int* __restrict__ rowbeg,
                                                const int* __restrict__ rowend,
                                                const int2* __restrict__ edata,
                                                const float* __restrict__ xw,
                                                const float* __restrict__ a,
                                                const float* __restrict__ bias,
                                                float* __restrict__ out) {
    constexpr int NPB = 256 / C;
    int tid = threadIdx.x;
    int g = tid / C;
    int lane = tid % C;
    int node = blockIdx.x * NPB + g;
    int start = rowbeg[node], end = rowend[node];
    float acc = 0.f;
    int j = start;
    for (; j + 1 < end; j += 2) {
        int2 e0 = edata[j];
        int2 e1 = edata[j + 1];
        float v0 = xw[(size_t)e0.x * C + lane];
        float v1 = xw[(size_t)e1.x * C + lane];
        acc = fmaf(__int_as_float(e0.y), v0, acc);
        acc = fmaf(__int_as_float(e1.y), v1, acc);
    }
    if (j < end) {
        int2 e0 = edata[j];
        acc = fmaf(__int_as_float(e0.y), xw[(size_t)e0.x * C + lane], acc);
    }
    float v = a[(size_t)node * C + lane] + acc + bias[lane];
    out[(size_t)node * C + lane] = v > 0.f ? v : 0.f;
}

// ---------------- collapsed FC head ----------------
__global__ __launch_bounds__(256) void k_w23(const float* __restrict__ fc2w,
                                             const float* __restrict__ fc3w,
                                             float* __restrict__ w23) {
    int gid = blockIdx.x * 256 + threadIdx.x;
    if (gid >= F1 * NC) return;
    int r = gid / NC, c = gid % NC;
    float acc = 0.f;
    for (int j = 0; j < F2; ++j) acc = fmaf(fc2w[r * F2 + j], fc3w[j * NC + c], acc);
    w23[gid] = acc;
}

__global__ __launch_bounds__(64) void k_bc(const float* __restrict__ fc1b,
                                           const float* __restrict__ fc2b,
                                           const float* __restrict__ fc3b,
                                           const float* __restrict__ fc3w,
                                           const float* __restrict__ w23,
                                           float* __restrict__ bc) {
    int c = threadIdx.x;
    if (c >= NC) return;
    float acc = fc3b[c];
    for (int k = 0; k < F1; ++k) acc = fmaf(fc1b[k], w23[k * NC + c], acc);
    for (int j = 0; j < F2; ++j) acc = fmaf(fc2b[j], fc3w[j * NC + c], acc);
    bc[c] = acc;
}

__global__ __launch_bounds__(256) void k_t1(const float* __restrict__ fc1w,
                                            const float* __restrict__ fc2w,
                                            float* __restrict__ t1) {
    int c = threadIdx.x & 127;
    int rh = threadIdx.x >> 7;
    int r0 = blockIdx.x * 16 + rh;
    float acc[8];
#pragma unroll
    for (int rr = 0; rr < 8; ++rr) acc[rr] = 0.f;
    for (int k = 0; k < F1; ++k) {
        float wv = fc2w[k * F2 + c];
#pragma unroll
        for (int rr = 0; rr < 8; ++rr)
            acc[rr] = fmaf(fc1w[(r0 + rr * 2) * F1 + k], wv, acc[rr]);
    }
#pragma unroll
    for (int rr = 0; rr < 8; ++rr) t1[(r0 + rr * 2) * F2 + c] = acc[rr];
}

__global__ __launch_bounds__(256) void k_wc(const float* __restrict__ t1,
                                            const float* __restrict__ fc3w,
                                            float* __restrict__ wc) {
    int gid = blockIdx.x * 256 + threadIdx.x;
    int r = gid >> 4, c = gid & 15;
    if (c >= NC) return;
    float acc = 0.f;
    for (int j = 0; j < F2; ++j) acc = fmaf(t1[r * F2 + j], fc3w[j * NC + c], acc);
    wc[r * NC + c] = acc;
}

__global__ __launch_bounds__(256) void k_out(const float* __restrict__ h3,
                                             const float* __restrict__ wc,
                                             const float* __restrict__ bc,
                                             float* __restrict__ out) {
    __shared__ float red[256 * 10];
    int g = blockIdx.x, tid = threadIdx.x;
    float acc[NC];
#pragma unroll
    for (int c = 0; c < NC; ++c) acc[c] = 0.f;
    for (int k = tid; k < FIN; k += 256) {
        float hv = h3[(size_t)g * FIN + k];
#pragma unroll
        for (int c = 0; c < NC; ++c) acc[c] = fmaf(hv, wc[k * NC + c], acc[c]);
    }
#pragma unroll
    for (int c = 0; c < NC; ++c) red[tid * 10 + c] = acc[c];
    __syncthreads();
    for (int s = 128; s > 0; s >>= 1) {
        if (tid < s) {
#pragma unroll
            for (int c = 0; c < NC; ++c) red[tid * 10 + c] += red[(tid + s) * 10 + c];
        }
        __syncthreads();
    }
    if (tid < NC) out[g * NC + tid] = red[tid] + bc[tid];
}

// ---------------- launch ----------------

extern "C" void kernel_launch(void* const* d_in, const int* in_sizes, int n_in,
                              void* d_out, int out_size, void* d_ws, size_t ws_size,
                              hipStream_t stream) {
    const float* x    = (const float*)d_in[0];
    const int*   ei   = (const int*)d_in[1];
    const float* ew   = (const float*)d_in[2];
    const float* W1_0 = (const float*)d_in[3];
    const float* W1_1 = (const float*)d_in[4];
    const float* b1   = (const float*)d_in[5];
    const float* W2_0 = (const float*)d_in[6];
    const float* W2_1 = (const float*)d_in[7];
    const float* b2   = (const float*)d_in[8];
    const float* W3_0 = (const float*)d_in[9];
    const float* W3_1 = (const float*)d_in[10];
    const float* b3   = (const float*)d_in[11];
    const float* fc1w = (const float*)d_in[12];
    const float* fc1b = (const float*)d_in[13];
    const float* fc2w = (const float*)d_in[14];
    const float* fc2b = (const float*)d_in[15];
    const float* fc3w = (const float*)d_in[16];
    const float* fc3b = (const float*)d_in[17];
    float* out = (float*)d_out;
    float* ws  = (float*)d_ws;

    const int* src = ei;        // edge_index[0]
    const int* dst = ei + NE;   // edge_index[1]

    // workspace layout (all regions 8B-aligned):
    //   dbuck [NBUCK*CAP int2]  -- dead after k_fin; A,B alias here (26.2MB <= 29.5MB)
    //   sbuck [NBUCK*CAP int2]  -- dead after k_deg2; edata aliases here
    //   D     [NN*HH floats]
    const size_t REG = (size_t)NBUCK * CAP;
    float* dinv  = ws;                         // [NN]
    int2*  dbuck = (int2*)(dinv + NN);         // [REG]
    int2*  sbuck = dbuck + REG;                // [REG]
    int2*  edata = sbuck;                      // alias
    float* D     = (float*)(sbuck + REG);      // [NN*HH]
    int*   rowbeg = (int*)(D + (size_t)NN * HH);  // [NN]
    int*   rowend = rowbeg + NN;               // [NN]
    int*   scur   = rowend + NN;               // [NBUCK] (pad to even)
    int*   dcur   = scur + ((NBUCK + 1) & ~1); // [NBUCK]
    float* w23    = (float*)(dcur + ((NBUCK + 1) & ~1));  // [256*9]
    float* bc     = w23 + F1 * NC;             // [9]

    float* A = (float*)dbuck;                  // [NN*HH] alias
    float* B = A + (size_t)NN * HH;            // [NN*HH] alias

    // graph preprocessing: dual partition -> dinv -> CSR finalize
    k_init<<<1, 256, 0, stream>>>(scur, dcur);
    k_part<0><<<NE / TILE, 256, 0, stream>>>(src, dst, ew, scur, sbuck);
    k_part<1><<<NE / TILE, 256, 0, stream>>>(src, dst, ew, dcur, dbuck);
    k_deg2<<<NBUCK, 512, 0, stream>>>(scur, sbuck, dinv);
    k_fin<<<NBUCK, 512, 0, stream>>>(dcur, dbuck, dinv, edata, rowbeg, rowend);

    // layer 1: 64 -> 32
    k_dual_gemm<TT, HH><<<NN / 256, 256, 0, stream>>>(x, W1_0, W1_1, A, B);
    k_gather<HH><<<NN / 8, 256, 0, stream>>>(rowbeg, rowend, edata, B, A, b1, D);

    // layer 2: 32 -> 32
    k_dual_gemm<HH, HH><<<NN / 256, 256, 0, stream>>>(D, W2_0, W2_1, A, B);
    k_gather<HH><<<NN / 8, 256, 0, stream>>>(rowbeg, rowend, edata, B, A, b2, D);

    // layer 3: 32 -> 16
    k_dual_gemm<HH, BSC><<<NN / 256, 256, 0, stream>>>(D, W3_0, W3_1, A, B);
    k_gather<BSC><<<NN / 16, 256, 0, stream>>>(rowbeg, rowend, edata, B, A, b3, D); // h3 in D

    // collapsed FC head
    k_w23<<<(F1 * NC + 255) / 256, 256, 0, stream>>>(fc2w, fc3w, w23);
    k_bc<<<1, 64, 0, stream>>>(fc1b, fc2b, fc3b, fc3w, w23, bc);
    float* T1 = A;   // [6400,128]
    k_t1<<<FIN / 16, 256, 0, stream>>>(fc1w, fc2w, T1);
    float* Wc = B;   // [6400,9]
    k_wc<<<FIN * 16 / 256, 256, 0, stream>>>(T1, fc3w, Wc);
    k_out<<<NG, 256, 0, stream>>>(D, Wc, bc, out);
}

// Round 7
// 662.492 us; speedup vs baseline: 2.0503x; 1.0591x over previous
//
#include <hip/hip_runtime.h>

// Problem constants
#define NN   102400      // nodes
#define NE   3276800     // edges
#define TT   64          // in channels
#define HH   32          // hidden
#define BSC  16          // conv3 out channels
#define NG   256         // graphs
#define NC   9           // classes
#define F1   256         // fc1 out
#define F2   128         // fc2 out
#define FIN  6400        // 400*16, fc1 in

#define NBUCK 200        // NN / 512 buckets (by node>>9)
#define CAP   18432      // slots per bucket region (mean 16384, +16 sigma)
#define TILE  8192       // edges per partition workgroup (NE/TILE = 400 wgs)

// ---------------- bucket cursor init ----------------

__global__ __launch_bounds__(256) void k_init(int* __restrict__ scur,
                                              int* __restrict__ dcur) {
    int t = threadIdx.x;
    if (t < NBUCK) { scur[t] = t * CAP; dcur[t] = t * CAP; }
}

// ---------------- LDS-staged partition by (src|dst)>>9 ----------------
// MODE 0: bucket by src, payload {src&511, ew}
// MODE 1: bucket by dst, payload {(src<<9)|(dst&511), ew}
template<int MODE>
__global__ __launch_bounds__(256) void k_part(const int* __restrict__ src,
                                              const int* __restrict__ dst,
                                              const float* __restrict__ ew,
                                              int* __restrict__ gcur,
                                              int2* __restrict__ outbuf) {
    __shared__ int hist[256];
    __shared__ int base[256];
    __shared__ int cur[256];
    __shared__ int gpos[256];
    __shared__ int2 stage[TILE];
    __shared__ unsigned char bkt[TILE];

    int t = threadIdx.x;
    int e0 = blockIdx.x * TILE;

    hist[t] = 0;
    __syncthreads();
    // phase 1: tile histogram
#pragma unroll
    for (int i = 0; i < TILE / 256; ++i) {
        int e = e0 + i * 256 + t;
        int key = MODE ? dst[e] : src[e];
        atomicAdd(&hist[key >> 9], 1);
    }
    __syncthreads();
    // phase 2: exclusive scan -> base
    int h = hist[t];
    base[t] = h;
    __syncthreads();
    for (int off = 1; off < 256; off <<= 1) {
        int add = (t >= off) ? base[t - off] : 0;
        __syncthreads();
        base[t] += add;
        __syncthreads();
    }
    int excl = base[t] - h;
    __syncthreads();
    base[t] = excl;
    cur[t] = excl;
    __syncthreads();
    // phase 3: place into LDS
#pragma unroll
    for (int i = 0; i < TILE / 256; ++i) {
        int e = e0 + i * 256 + t;
        int s = src[e];
        int w = __float_as_int(ew[e]);
        int key, pack;
        if (MODE) { int d = dst[e]; key = d; pack = (s << 9) | (d & 511); }
        else      { key = s; pack = s & 511; }
        int b = key >> 9;
        int p = atomicAdd(&cur[b], 1);
        stage[p] = make_int2(pack, w);
        bkt[p] = (unsigned char)b;
    }
    __syncthreads();
    // phase 4: claim contiguous global ranges in this bucket's region
    if (t < NBUCK && h > 0) gpos[t] = atomicAdd(&gcur[t], h);
    __syncthreads();
    // phase 5: coalesced flush
#pragma unroll
    for (int i = 0; i < TILE / 256; ++i) {
        int p = i * 256 + t;
        int b = bkt[p];
        outbuf[gpos[b] + (p - base[b])] = stage[p];
    }
}

// ---------------- per-src-bucket weighted degree -> dinv (LDS histogram) ---

__global__ __launch_bounds__(512) void k_deg2(const int* __restrict__ scur,
                                              const int2* __restrict__ sbuck,
                                              float* __restrict__ dinv) {
    __shared__ float acc[512];
    int b = blockIdx.x, t = threadIdx.x;
    acc[t] = 0.f;
    __syncthreads();
    int lo = b * CAP, hi = scur[b];
    for (int j = lo + t; j < hi; j += 512) {
        int2 e = sbuck[j];
        atomicAdd(&acc[e.x], __int_as_float(e.y));
    }
    __syncthreads();
    float v = acc[t];
    dinv[b * 512 + t] = v > 0.f ? rsqrtf(v) : 0.f;
}

// ---------------- per-dst-bucket CSR finalize (LDS hist+scan+cursors) ------
// edata[slot] = {src, lapw}; rowbeg/rowend delimit each node's edges.

__global__ __launch_bounds__(512) void k_fin(const int* __restrict__ dcur,
                                             const int2* __restrict__ dbuck,
                                             const float* __restrict__ dinv,
                                             int2* __restrict__ edata,
                                             int* __restrict__ rowbeg,
                                             int* __restrict__ rowend) {
    __shared__ float dl[512];
    __shared__ int cnt[512];
    __shared__ int base[512];
    __shared__ int cur[512];
    int b = blockIdx.x, t = threadIdx.x;
    dl[t] = dinv[b * 512 + t];
    cnt[t] = 0;
    __syncthreads();
    int lo = b * CAP, hi = dcur[b];
    for (int j = lo + t; j < hi; j += 512)
        atomicAdd(&cnt[dbuck[j].x & 511], 1);
    __syncthreads();
    int h = cnt[t];
    base[t] = h;
    __syncthreads();
    for (int off = 1; off < 512; off <<= 1) {
        int add = (t >= off) ? base[t - off] : 0;
        __syncthreads();
        base[t] += add;
        __syncthreads();
    }
    int beg = lo + base[t] - h;
    rowbeg[b * 512 + t] = beg;
    rowend[b * 512 + t] = beg + h;
    cur[t] = beg;
    __syncthreads();
    for (int j = lo + t; j < hi; j += 512) {
        int2 e = dbuck[j];
        int dlow = e.x & 511;
        int s = e.x >> 9;
        float lw = -dinv[s] * __int_as_float(e.y) * dl[dlow];
        int slot = atomicAdd(&cur[dlow], 1);
        edata[slot] = make_int2(s, __float_as_int(lw));
    }
}

// ---------------- per-row src-sort (pure locality optimization) ------------
// One wave per CSR row: 64-lane in-register bitonic sort on (src<<32)|lapw.
// Rows longer than 64 are left unsorted (correctness unaffected).

__global__ __launch_bounds__(256) void k_sortrows(const int* __restrict__ rowbeg,
                                                  const int* __restrict__ rowend,
                                                  int2* __restrict__ edata) {
    int wave = threadIdx.x >> 6;
    int lane = threadIdx.x & 63;
    int node = blockIdx.x * 4 + wave;
    int beg = rowbeg[node], end = rowend[node];
    int len = end - beg;
    if (len > 64 || len <= 1) return;   // wave-uniform branch
    unsigned long long key;
    if (lane < len) {
        int2 e = edata[beg + lane];
        key = ((unsigned long long)(unsigned)e.x << 32) | (unsigned)e.y;
    } else {
        key = ~0ULL;
    }
#pragma unroll
    for (int k = 2; k <= 64; k <<= 1) {
#pragma unroll
        for (int j = k >> 1; j >= 1; j >>= 1) {
            unsigned long long other = __shfl_xor(key, j, 64);
            bool lower = (lane & j) == 0;
            bool asc   = (lane & k) == 0;
            unsigned long long mn = key < other ? key : other;
            unsigned long long mx = key < other ? other : key;
            key = (lower == asc) ? mn : mx;
        }
    }
    if (lane < len) {
        edata[beg + lane] = make_int2((int)(key >> 32),
                                      (int)(unsigned)(key & 0xFFFFFFFFu));
    }
}

// ---------------- per-node dual GEMM (h@W0 and h@W1) ----------------
template<int CIN, int COUT>
__global__ __launch_bounds__(256) void k_dual_gemm(const float* __restrict__ in,
                                                   const float* __restrict__ W0,
                                                   const float* __restrict__ W1,
                                                   float* __restrict__ o0,
                                                   float* __restrict__ o1) {
    int node = blockIdx.x * 256 + threadIdx.x;
    const float* row = in + (size_t)node * CIN;
    float a0[COUT], a1[COUT];
#pragma unroll
    for (int c = 0; c < COUT; ++c) { a0[c] = 0.f; a1[c] = 0.f; }
    for (int k = 0; k < CIN; ++k) {
        float xv = row[k];
#pragma unroll
        for (int c = 0; c < COUT; ++c) {
            a0[c] = fmaf(xv, W0[k * COUT + c], a0[c]);
            a1[c] = fmaf(xv, W1[k * COUT + c], a1[c]);
        }
    }
#pragma unroll
    for (int c = 0; c < COUT; ++c) {
        o0[(size_t)node * COUT + c] = a0[c];
        o1[(size_t)node * COUT + c] = a1[c];
    }
}

// ---------------- CSR gather fused with bias+relu --------------------------
// out[n,c] = relu(a[n,c] + sum_e lapw_e * xw[src_e, c] + bias[c])
template<int C>
__global__ __launch_bounds__(256) void k_gather(const int* __restrict__ rowbeg,
                                                const int* __restrict__ rowend,
                                                const int2* __restrict__ edata,
                                                const float* __restrict__ xw,
                                                const float* __restrict__ a,
                                                const float* __restrict__ bias,
                                                float* __restrict__ out) {
    constexpr int NPB = 256 / C;
    int tid = threadIdx.x;
    int g = tid / C;
    int lane = tid % C;
    int node = blockIdx.x * NPB + g;
    int start = rowbeg[node], end = rowend[node];
    float acc = 0.f;
    int j = start;
    for (; j + 3 < end; j += 4) {
        int2 e0 = edata[j];
        int2 e1 = edata[j + 1];
        int2 e2 = edata[j + 2];
        int2 e3 = edata[j + 3];
        float v0 = xw[(size_t)e0.x * C + lane];
        float v1 = xw[(size_t)e1.x * C + lane];
        float v2 = xw[(size_t)e2.x * C + lane];
        float v3 = xw[(size_t)e3.x * C + lane];
        acc = fmaf(__int_as_float(e0.y), v0, acc);
        acc = fmaf(__int_as_float(e1.y), v1, acc);
        acc = fmaf(__int_as_float(e2.y), v2, acc);
        acc = fmaf(__int_as_float(e3.y), v3, acc);
    }
    for (; j < end; ++j) {
        int2 e0 = edata[j];
        acc = fmaf(__int_as_float(e0.y), xw[(size_t)e0.x * C + lane], acc);
    }
    float v = a[(size_t)node * C + lane] + acc + bias[lane];
    out[(size_t)node * C + lane] = v > 0.f ? v : 0.f;
}

// ---------------- collapsed FC head ----------------
__global__ __launch_bounds__(256) void k_w23(const float* __restrict__ fc2w,
                                             const float* __restrict__ fc3w,
                                             float* __restrict__ w23) {
    int gid = blockIdx.x * 256 + threadIdx.x;
    if (gid >= F1 * NC) return;
    int r = gid / NC, c = gid % NC;
    float acc = 0.f;
    for (int j = 0; j < F2; ++j) acc = fmaf(fc2w[r * F2 + j], fc3w[j * NC + c], acc);
    w23[gid] = acc;
}

__global__ __launch_bounds__(64) void k_bc(const float* __restrict__ fc1b,
                                           const float* __restrict__ fc2b,
                                           const float* __restrict__ fc3b,
                                           const float* __restrict__ fc3w,
                                           const float* __restrict__ w23,
                                           float* __restrict__ bc) {
    int c = threadIdx.x;
    if (c >= NC) return;
    float acc = fc3b[c];
    for (int k = 0; k < F1; ++k) acc = fmaf(fc1b[k], w23[k * NC + c], acc);
    for (int j = 0; j < F2; ++j) acc = fmaf(fc2b[j], fc3w[j * NC + c], acc);
    bc[c] = acc;
}

__global__ __launch_bounds__(256) void k_t1(const float* __restrict__ fc1w,
                                            const float* __restrict__ fc2w,
                                            float* __restrict__ t1) {
    int c = threadIdx.x & 127;
    int rh = threadIdx.x >> 7;
    int r0 = blockIdx.x * 16 + rh;
    float acc[8];
#pragma unroll
    for (int rr = 0; rr < 8; ++rr) acc[rr] = 0.f;
    for (int k = 0; k < F1; ++k) {
        float wv = fc2w[k * F2 + c];
#pragma unroll
        for (int rr = 0; rr < 8; ++rr)
            acc[rr] = fmaf(fc1w[(r0 + rr * 2) * F1 + k], wv, acc[rr]);
    }
#pragma unroll
    for (int rr = 0; rr < 8; ++rr) t1[(r0 + rr * 2) * F2 + c] = acc[rr];
}

__global__ __launch_bounds__(256) void k_wc(const float* __restrict__ t1,
                                            const float* __restrict__ fc3w,
                                            float* __restrict__ wc) {
    int gid = blockIdx.x * 256 + threadIdx.x;
    int r = gid >> 4, c = gid & 15;
    if (c >= NC) return;
    float acc = 0.f;
    for (int j = 0; j < F2; ++j) acc = fmaf(t1[r * F2 + j], fc3w[j * NC + c], acc);
    wc[r * NC + c] = acc;
}

__global__ __launch_bounds__(256) void k_out(const float* __restrict__ h3,
                                             const float* __restrict__ wc,
                                             const float* __restrict__ bc,
                                             float* __restrict__ out) {
    __shared__ float red[256 * 10];
    int g = blockIdx.x, tid = threadIdx.x;
    float acc[NC];
#pragma unroll
    for (int c = 0; c < NC; ++c) acc[c] = 0.f;
    for (int k = tid; k < FIN; k += 256) {
        float hv = h3[(size_t)g * FIN + k];
#pragma unroll
        for (int c = 0; c < NC; ++c) acc[c] = fmaf(hv, wc[k * NC + c], acc[c]);
    }
#pragma unroll
    for (int c = 0; c < NC; ++c) red[tid * 10 + c] = acc[c];
    __syncthreads();
    for (int s = 128; s > 0; s >>= 1) {
        if (tid < s) {
#pragma unroll
            for (int c = 0; c < NC; ++c) red[tid * 10 + c] += red[(tid + s) * 10 + c];
        }
        __syncthreads();
    }
    if (tid < NC) out[g * NC + tid] = red[tid] + bc[tid];
}

// ---------------- launch ----------------

extern "C" void kernel_launch(void* const* d_in, const int* in_sizes, int n_in,
                              void* d_out, int out_size, void* d_ws, size_t ws_size,
                              hipStream_t stream) {
    const float* x    = (const float*)d_in[0];
    const int*   ei   = (const int*)d_in[1];
    const float* ew   = (const float*)d_in[2];
    const float* W1_0 = (const float*)d_in[3];
    const float* W1_1 = (const float*)d_in[4];
    const float* b1   = (const float*)d_in[5];
    const float* W2_0 = (const float*)d_in[6];
    const float* W2_1 = (const float*)d_in[7];
    const float* b2   = (const float*)d_in[8];
    const float* W3_0 = (const float*)d_in[9];
    const float* W3_1 = (const float*)d_in[10];
    const float* b3   = (const float*)d_in[11];
    const float* fc1w = (const float*)d_in[12];
    const float* fc1b = (const float*)d_in[13];
    const float* fc2w = (const float*)d_in[14];
    const float* fc2b = (const float*)d_in[15];
    const float* fc3w = (const float*)d_in[16];
    const float* fc3b = (const float*)d_in[17];
    float* out = (float*)d_out;
    float* ws  = (float*)d_ws;

    const int* src = ei;        // edge_index[0]
    const int* dst = ei + NE;   // edge_index[1]

    // workspace layout (all regions 8B-aligned):
    //   dbuck [NBUCK*CAP int2]  -- dead after k_fin; A,B alias here (26.2MB <= 29.5MB)
    //   sbuck [NBUCK*CAP int2]  -- dead after k_deg2; edata aliases here
    //   D     [NN*HH floats]
    const size_t REG = (size_t)NBUCK * CAP;
    float* dinv  = ws;                         // [NN]
    int2*  dbuck = (int2*)(dinv + NN);         // [REG]
    int2*  sbuck = dbuck + REG;                // [REG]
    int2*  edata = sbuck;                      // alias
    float* D     = (float*)(sbuck + REG);      // [NN*HH]
    int*   rowbeg = (int*)(D + (size_t)NN * HH);  // [NN]
    int*   rowend = rowbeg + NN;               // [NN]
    int*   scur   = rowend + NN;               // [NBUCK] (pad to even)
    int*   dcur   = scur + ((NBUCK + 1) & ~1); // [NBUCK]
    float* w23    = (float*)(dcur + ((NBUCK + 1) & ~1));  // [256*9]
    float* bc     = w23 + F1 * NC;             // [9]

    float* A = (float*)dbuck;                  // [NN*HH] alias
    float* B = A + (size_t)NN * HH;            // [NN*HH] alias

    // graph preprocessing: dual partition -> dinv -> CSR finalize -> row sort
    k_init<<<1, 256, 0, stream>>>(scur, dcur);
    k_part<0><<<NE / TILE, 256, 0, stream>>>(src, dst, ew, scur, sbuck);
    k_part<1><<<NE / TILE, 256, 0, stream>>>(src, dst, ew, dcur, dbuck);
    k_deg2<<<NBUCK, 512, 0, stream>>>(scur, sbuck, dinv);
    k_fin<<<NBUCK, 512, 0, stream>>>(dcur, dbuck, dinv, edata, rowbeg, rowend);
    k_sortrows<<<NN / 4, 256, 0, stream>>>(rowbeg, rowend, edata);

    // layer 1: 64 -> 32
    k_dual_gemm<TT, HH><<<NN / 256, 256, 0, stream>>>(x, W1_0, W1_1, A, B);
    k_gather<HH><<<NN / 8, 256, 0, stream>>>(rowbeg, rowend, edata, B, A, b1, D);

    // layer 2: 32 -> 32
    k_dual_gemm<HH, HH><<<NN / 256, 256, 0, stream>>>(D, W2_0, W2_1, A, B);
    k_gather<HH><<<NN / 8, 256, 0, stream>>>(rowbeg, rowend, edata, B, A, b2, D);

    // layer 3: 32 -> 16
    k_dual_gemm<HH, BSC><<<NN / 256, 256, 0, stream>>>(D, W3_0, W3_1, A, B);
    k_gather<BSC><<<NN / 16, 256, 0, stream>>>(rowbeg, rowend, edata, B, A, b3, D); // h3 in D

    // collapsed FC head
    k_w23<<<(F1 * NC + 255) / 256, 256, 0, stream>>>(fc2w, fc3w, w23);
    k_bc<<<1, 64, 0, stream>>>(fc1b, fc2b, fc3b, fc3w, w23, bc);
    float* T1 = A;   // [6400,128]
    k_t1<<<FIN / 16, 256, 0, stream>>>(fc1w, fc2w, T1);
    float* Wc = B;   // [6400,9]
    k_wc<<<FIN * 16 / 256, 256, 0, stream>>>(T1, fc3w, Wc);
    k_out<<<NG, 256, 0, stream>>>(D, Wc, bc, out);
}

// Round 8
// 632.459 us; speedup vs baseline: 2.1476x; 1.0475x over previous
//
#include <hip/hip_runtime.h>

// Problem constants
#define NN   102400      // nodes
#define NE   3276800     // edges
#define TT   64          // in channels
#define HH   32          // hidden
#define BSC  16          // conv3 out channels
#define NG   256         // graphs
#define NC   9           // classes
#define F1   256         // fc1 out
#define F2   128         // fc2 out
#define FIN  6400        // 400*16, fc1 in

#define NBUCK 200        // NN / 512 buckets (by node>>9)
#define CAP   18432      // slots per bucket region (mean 16384, +16 sigma)
#define TILE  8192       // edges per partition workgroup (NE/TILE = 400 wgs)

// ---------------- bucket cursor init ----------------

__global__ __launch_bounds__(256) void k_init(int* __restrict__ scur,
                                              int* __restrict__ dcur) {
    int t = threadIdx.x;
    if (t < NBUCK) { scur[t] = t * CAP; dcur[t] = t * CAP; }
}

// ---------------- LDS-staged partition by (src|dst)>>9 ----------------
// MODE 0: bucket by src, payload {src&511, ew}
// MODE 1: bucket by dst, payload {(src<<9)|(dst&511), ew}
template<int MODE>
__global__ __launch_bounds__(256) void k_part(const int* __restrict__ src,
                                              const int* __restrict__ dst,
                                              const float* __restrict__ ew,
                                              int* __restrict__ gcur,
                                              int2* __restrict__ outbuf) {
    __shared__ int hist[256];
    __shared__ int base[256];
    __shared__ int cur[256];
    __shared__ int gpos[256];
    __shared__ int2 stage[TILE];
    __shared__ unsigned char bkt[TILE];

    int t = threadIdx.x;
    int e0 = blockIdx.x * TILE;

    hist[t] = 0;
    __syncthreads();
    // phase 1: tile histogram
#pragma unroll
    for (int i = 0; i < TILE / 256; ++i) {
        int e = e0 + i * 256 + t;
        int key = MODE ? dst[e] : src[e];
        atomicAdd(&hist[key >> 9], 1);
    }
    __syncthreads();
    // phase 2: exclusive scan -> base
    int h = hist[t];
    base[t] = h;
    __syncthreads();
    for (int off = 1; off < 256; off <<= 1) {
        int add = (t >= off) ? base[t - off] : 0;
        __syncthreads();
        base[t] += add;
        __syncthreads();
    }
    int excl = base[t] - h;
    __syncthreads();
    base[t] = excl;
    cur[t] = excl;
    __syncthreads();
    // phase 3: place into LDS
#pragma unroll
    for (int i = 0; i < TILE / 256; ++i) {
        int e = e0 + i * 256 + t;
        int s = src[e];
        int w = __float_as_int(ew[e]);
        int key, pack;
        if (MODE) { int d = dst[e]; key = d; pack = (s << 9) | (d & 511); }
        else      { key = s; pack = s & 511; }
        int b = key >> 9;
        int p = atomicAdd(&cur[b], 1);
        stage[p] = make_int2(pack, w);
        bkt[p] = (unsigned char)b;
    }
    __syncthreads();
    // phase 4: claim contiguous global ranges in this bucket's region
    if (t < NBUCK && h > 0) gpos[t] = atomicAdd(&gcur[t], h);
    __syncthreads();
    // phase 5: coalesced flush
#pragma unroll
    for (int i = 0; i < TILE / 256; ++i) {
        int p = i * 256 + t;
        int b = bkt[p];
        outbuf[gpos[b] + (p - base[b])] = stage[p];
    }
}

// ---------------- per-src-bucket weighted degree -> dinv (LDS histogram) ---

__global__ __launch_bounds__(512) void k_deg2(const int* __restrict__ scur,
                                              const int2* __restrict__ sbuck,
                                              float* __restrict__ dinv) {
    __shared__ float acc[512];
    int b = blockIdx.x, t = threadIdx.x;
    acc[t] = 0.f;
    __syncthreads();
    int lo = b * CAP, hi = scur[b];
    for (int j = lo + t; j < hi; j += 512) {
        int2 e = sbuck[j];
        atomicAdd(&acc[e.x], __int_as_float(e.y));
    }
    __syncthreads();
    float v = acc[t];
    dinv[b * 512 + t] = v > 0.f ? rsqrtf(v) : 0.f;
}

// ---------------- per-dst-bucket CSR finalize (LDS hist+scan+cursors) ------
// edata[slot] = {src, lapw}; rowbeg/rowend delimit each node's edges.

__global__ __launch_bounds__(512) void k_fin(const int* __restrict__ dcur,
                                             const int2* __restrict__ dbuck,
                                             const float* __restrict__ dinv,
                                             int2* __restrict__ edata,
                                             int* __restrict__ rowbeg,
                                             int* __restrict__ rowend) {
    __shared__ float dl[512];
    __shared__ int cnt[512];
    __shared__ int base[512];
    __shared__ int cur[512];
    int b = blockIdx.x, t = threadIdx.x;
    dl[t] = dinv[b * 512 + t];
    cnt[t] = 0;
    __syncthreads();
    int lo = b * CAP, hi = dcur[b];
    for (int j = lo + t; j < hi; j += 512)
        atomicAdd(&cnt[dbuck[j].x & 511], 1);
    __syncthreads();
    int h = cnt[t];
    base[t] = h;
    __syncthreads();
    for (int off = 1; off < 512; off <<= 1) {
        int add = (t >= off) ? base[t - off] : 0;
        __syncthreads();
        base[t] += add;
        __syncthreads();
    }
    int beg = lo + base[t] - h;
    rowbeg[b * 512 + t] = beg;
    rowend[b * 512 + t] = beg + h;
    cur[t] = beg;
    __syncthreads();
    for (int j = lo + t; j < hi; j += 512) {
        int2 e = dbuck[j];
        int dlow = e.x & 511;
        int s = e.x >> 9;
        float lw = -dinv[s] * __int_as_float(e.y) * dl[dlow];
        int slot = atomicAdd(&cur[dlow], 1);
        edata[slot] = make_int2(s, __float_as_int(lw));
    }
}

// ---------------- per-row src-sort (pure locality optimization) ------------
// One wave per CSR row: 64-lane in-register bitonic sort on (src<<32)|lapw.
// Rows longer than 64 are left unsorted (correctness unaffected).

__global__ __launch_bounds__(256) void k_sortrows(const int* __restrict__ rowbeg,
                                                  const int* __restrict__ rowend,
                                                  int2* __restrict__ edata) {
    int wave = threadIdx.x >> 6;
    int lane = threadIdx.x & 63;
    int node = blockIdx.x * 4 + wave;
    int beg = rowbeg[node], end = rowend[node];
    int len = end - beg;
    if (len > 64 || len <= 1) return;   // wave-uniform branch
    unsigned long long key;
    if (lane < len) {
        int2 e = edata[beg + lane];
        key = ((unsigned long long)(unsigned)e.x << 32) | (unsigned)e.y;
    } else {
        key = ~0ULL;
    }
#pragma unroll
    for (int k = 2; k <= 64; k <<= 1) {
#pragma unroll
        for (int j = k >> 1; j >= 1; j >>= 1) {
            unsigned long long other = __shfl_xor(key, j, 64);
            bool lower = (lane & j) == 0;
            bool asc   = (lane & k) == 0;
            unsigned long long mn = key < other ? key : other;
            unsigned long long mx = key < other ? other : key;
            key = (lower == asc) ? mn : mx;
        }
    }
    if (lane < len) {
        edata[beg + lane] = make_int2((int)(key >> 32),
                                      (int)(unsigned)(key & 0xFFFFFFFFu));
    }
}

// ---------------- per-node dual GEMM (h@W0 and h@W1) ----------------
template<int CIN, int COUT>
__global__ __launch_bounds__(256) void k_dual_gemm(const float* __restrict__ in,
                                                   const float* __restrict__ W0,
                                                   const float* __restrict__ W1,
                                                   float* __restrict__ o0,
                                                   float* __restrict__ o1) {
    int node = blockIdx.x * 256 + threadIdx.x;
    const float* row = in + (size_t)node * CIN;
    float a0[COUT], a1[COUT];
#pragma unroll
    for (int c = 0; c < COUT; ++c) { a0[c] = 0.f; a1[c] = 0.f; }
    for (int k = 0; k < CIN; ++k) {
        float xv = row[k];
#pragma unroll
        for (int c = 0; c < COUT; ++c) {
            a0[c] = fmaf(xv, W0[k * COUT + c], a0[c]);
            a1[c] = fmaf(xv, W1[k * COUT + c], a1[c]);
        }
    }
#pragma unroll
    for (int c = 0; c < COUT; ++c) {
        o0[(size_t)node * COUT + c] = a0[c];
        o1[(size_t)node * COUT + c] = a1[c];
    }
}

// ---------------- CSR gather fused with bias+relu --------------------------
// out[n,c] = relu(a[n,c] + sum_e lapw_e * xw[src_e, c] + bias[c])
// float2 per lane (C/2 lanes per edge), 8-deep load pipeline for MLP.
template<int C>
__global__ __launch_bounds__(256) void k_gather(const int* __restrict__ rowbeg,
                                                const int* __restrict__ rowend,
                                                const int2* __restrict__ edata,
                                                const float* __restrict__ xw,
                                                const float* __restrict__ a,
                                                const float* __restrict__ bias,
                                                float* __restrict__ out) {
    constexpr int L = C / 2;          // lanes per edge (float2 each)
    constexpr int NPB = 256 / L;      // nodes per block
    int tid = threadIdx.x;
    int g = tid / L;
    int lane = tid % L;
    int node = blockIdx.x * NPB + g;
    int start = rowbeg[node], end = rowend[node];
    const float2* xw2 = (const float2*)xw;
    float accx = 0.f, accy = 0.f;
    int j = start;
    for (; j + 7 < end; j += 8) {
        int2 e[8];
        float2 v[8];
#pragma unroll
        for (int u = 0; u < 8; ++u) e[u] = edata[j + u];
#pragma unroll
        for (int u = 0; u < 8; ++u) v[u] = xw2[(size_t)e[u].x * L + lane];
#pragma unroll
        for (int u = 0; u < 8; ++u) {
            float w = __int_as_float(e[u].y);
            accx = fmaf(w, v[u].x, accx);
            accy = fmaf(w, v[u].y, accy);
        }
    }
    for (; j < end; ++j) {
        int2 e0 = edata[j];
        float2 v0 = xw2[(size_t)e0.x * L + lane];
        float w = __int_as_float(e0.y);
        accx = fmaf(w, v0.x, accx);
        accy = fmaf(w, v0.y, accy);
    }
    float2 av = ((const float2*)a)[(size_t)node * L + lane];
    float2 bv = ((const float2*)bias)[lane];
    float rx = av.x + accx + bv.x;
    float ry = av.y + accy + bv.y;
    float2 r;
    r.x = rx > 0.f ? rx : 0.f;
    r.y = ry > 0.f ? ry : 0.f;
    ((float2*)out)[(size_t)node * L + lane] = r;
}

// ---------------- collapsed FC head ----------------
__global__ __launch_bounds__(256) void k_w23(const float* __restrict__ fc2w,
                                             const float* __restrict__ fc3w,
                                             float* __restrict__ w23) {
    int gid = blockIdx.x * 256 + threadIdx.x;
    if (gid >= F1 * NC) return;
    int r = gid / NC, c = gid % NC;
    float acc = 0.f;
    for (int j = 0; j < F2; ++j) acc = fmaf(fc2w[r * F2 + j], fc3w[j * NC + c], acc);
    w23[gid] = acc;
}

__global__ __launch_bounds__(64) void k_bc(const float* __restrict__ fc1b,
                                           const float* __restrict__ fc2b,
                                           const float* __restrict__ fc3b,
                                           const float* __restrict__ fc3w,
                                           const float* __restrict__ w23,
                                           float* __restrict__ bc) {
    int c = threadIdx.x;
    if (c >= NC) return;
    float acc = fc3b[c];
    for (int k = 0; k < F1; ++k) acc = fmaf(fc1b[k], w23[k * NC + c], acc);
    for (int j = 0; j < F2; ++j) acc = fmaf(fc2b[j], fc3w[j * NC + c], acc);
    bc[c] = acc;
}

__global__ __launch_bounds__(256) void k_t1(const float* __restrict__ fc1w,
                                            const float* __restrict__ fc2w,
                                            float* __restrict__ t1) {
    int c = threadIdx.x & 127;
    int rh = threadIdx.x >> 7;
    int r0 = blockIdx.x * 16 + rh;
    float acc[8];
#pragma unroll
    for (int rr = 0; rr < 8; ++rr) acc[rr] = 0.f;
    for (int k = 0; k < F1; ++k) {
        float wv = fc2w[k * F2 + c];
#pragma unroll
        for (int rr = 0; rr < 8; ++rr)
            acc[rr] = fmaf(fc1w[(r0 + rr * 2) * F1 + k], wv, acc[rr]);
    }
#pragma unroll
    for (int rr = 0; rr < 8; ++rr) t1[(r0 + rr * 2) * F2 + c] = acc[rr];
}

__global__ __launch_bounds__(256) void k_wc(const float* __restrict__ t1,
                                            const float* __restrict__ fc3w,
                                            float* __restrict__ wc) {
    int gid = blockIdx.x * 256 + threadIdx.x;
    int r = gid >> 4, c = gid & 15;
    if (c >= NC) return;
    float acc = 0.f;
    for (int j = 0; j < F2; ++j) acc = fmaf(t1[r * F2 + j], fc3w[j * NC + c], acc);
    wc[r * NC + c] = acc;
}

__global__ __launch_bounds__(256) void k_out(const float* __restrict__ h3,
                                             const float* __restrict__ wc,
                                             const float* __restrict__ bc,
                                             float* __restrict__ out) {
    __shared__ float red[256 * 10];
    int g = blockIdx.x, tid = threadIdx.x;
    float acc[NC];
#pragma unroll
    for (int c = 0; c < NC; ++c) acc[c] = 0.f;
    for (int k = tid; k < FIN; k += 256) {
        float hv = h3[(size_t)g * FIN + k];
#pragma unroll
        for (int c = 0; c < NC; ++c) acc[c] = fmaf(hv, wc[k * NC + c], acc[c]);
    }
#pragma unroll
    for (int c = 0; c < NC; ++c) red[tid * 10 + c] = acc[c];
    __syncthreads();
    for (int s = 128; s > 0; s >>= 1) {
        if (tid < s) {
#pragma unroll
            for (int c = 0; c < NC; ++c) red[tid * 10 + c] += red[(tid + s) * 10 + c];
        }
        __syncthreads();
    }
    if (tid < NC) out[g * NC + tid] = red[tid] + bc[tid];
}

// ---------------- launch ----------------

extern "C" void kernel_launch(void* const* d_in, const int* in_sizes, int n_in,
                              void* d_out, int out_size, void* d_ws, size_t ws_size,
                              hipStream_t stream) {
    const float* x    = (const float*)d_in[0];
    const int*   ei   = (const int*)d_in[1];
    const float* ew   = (const float*)d_in[2];
    const float* W1_0 = (const float*)d_in[3];
    const float* W1_1 = (const float*)d_in[4];
    const float* b1   = (const float*)d_in[5];
    const float* W2_0 = (const float*)d_in[6];
    const float* W2_1 = (const float*)d_in[7];
    const float* b2   = (const float*)d_in[8];
    const float* W3_0 = (const float*)d_in[9];
    const float* W3_1 = (const float*)d_in[10];
    const float* b3   = (const float*)d_in[11];
    const float* fc1w = (const float*)d_in[12];
    const float* fc1b = (const float*)d_in[13];
    const float* fc2w = (const float*)d_in[14];
    const float* fc2b = (const float*)d_in[15];
    const float* fc3w = (const float*)d_in[16];
    const float* fc3b = (const float*)d_in[17];
    float* out = (float*)d_out;
    float* ws  = (float*)d_ws;

    const int* src = ei;        // edge_index[0]
    const int* dst = ei + NE;   // edge_index[1]

    // workspace layout (all regions 8B-aligned):
    //   dbuck [NBUCK*CAP int2]  -- dead after k_fin; A,B alias here (26.2MB <= 29.5MB)
    //   sbuck [NBUCK*CAP int2]  -- dead after k_deg2; edata aliases here
    //   D     [NN*HH floats]
    const size_t REG = (size_t)NBUCK * CAP;
    float* dinv  = ws;                         // [NN]
    int2*  dbuck = (int2*)(dinv + NN);         // [REG]
    int2*  sbuck = dbuck + REG;                // [REG]
    int2*  edata = sbuck;                      // alias
    float* D     = (float*)(sbuck + REG);      // [NN*HH]
    int*   rowbeg = (int*)(D + (size_t)NN * HH);  // [NN]
    int*   rowend = rowbeg + NN;               // [NN]
    int*   scur   = rowend + NN;               // [NBUCK] (pad to even)
    int*   dcur   = scur + ((NBUCK + 1) & ~1); // [NBUCK]
    float* w23    = (float*)(dcur + ((NBUCK + 1) & ~1));  // [256*9]
    float* bc     = w23 + F1 * NC;             // [9]

    float* A = (float*)dbuck;                  // [NN*HH] alias
    float* B = A + (size_t)NN * HH;            // [NN*HH] alias

    // graph preprocessing: dual partition -> dinv -> CSR finalize -> row sort
    k_init<<<1, 256, 0, stream>>>(scur, dcur);
    k_part<0><<<NE / TILE, 256, 0, stream>>>(src, dst, ew, scur, sbuck);
    k_part<1><<<NE / TILE, 256, 0, stream>>>(src, dst, ew, dcur, dbuck);
    k_deg2<<<NBUCK, 512, 0, stream>>>(scur, sbuck, dinv);
    k_fin<<<NBUCK, 512, 0, stream>>>(dcur, dbuck, dinv, edata, rowbeg, rowend);
    k_sortrows<<<NN / 4, 256, 0, stream>>>(rowbeg, rowend, edata);

    // layer 1: 64 -> 32
    k_dual_gemm<TT, HH><<<NN / 256, 256, 0, stream>>>(x, W1_0, W1_1, A, B);
    k_gather<HH><<<NN / 16, 256, 0, stream>>>(rowbeg, rowend, edata, B, A, b1, D);

    // layer 2: 32 -> 32
    k_dual_gemm<HH, HH><<<NN / 256, 256, 0, stream>>>(D, W2_0, W2_1, A, B);
    k_gather<HH><<<NN / 16, 256, 0, stream>>>(rowbeg, rowend, edata, B, A, b2, D);

    // layer 3: 32 -> 16
    k_dual_gemm<HH, BSC><<<NN / 256, 256, 0, stream>>>(D, W3_0, W3_1, A, B);
    k_gather<BSC><<<NN / 32, 256, 0, stream>>>(rowbeg, rowend, edata, B, A, b3, D); // h3 in D

    // collapsed FC head
    k_w23<<<(F1 * NC + 255) / 256, 256, 0, stream>>>(fc2w, fc3w, w23);
    k_bc<<<1, 64, 0, stream>>>(fc1b, fc2b, fc3b, fc3w, w23, bc);
    float* T1 = A;   // [6400,128]
    k_t1<<<FIN / 16, 256, 0, stream>>>(fc1w, fc2w, T1);
    float* Wc = B;   // [6400,9]
    k_wc<<<FIN * 16 / 256, 256, 0, stream>>>(T1, fc3w, Wc);
    k_out<<<NG, 256, 0, stream>>>(D, Wc, bc, out);
}